// Round 5
// baseline (1159.510 us; speedup 1.0000x reference)
//
#include <hip/hip_runtime.h>
#include <math.h>

// PQLayer forward, MI355X — R12: fused, m-GROUP blocks, 8KB write bursts.
//   x: (B,512) fp32   C: (64,256,8) fp32
//   out0 x_hat (B,512) = C[m,k*,:]   out1 codes (B,64,256) = one_hot(k*)
//
// Evidence R8-R11: every argmax-internal change ±5us; only structural
// deletion won (-44). Fused kernel residue ~440us vs ~181us write floor,
// while the harness fill proves 6.25 TB/s on this buffer. Effective write
// BW ~2.6 TB/s -> DRAM page thrash: m-uniform blocks max out at 1KB
// contiguous per store burst, 64KB jumps between bursts (~256B per HBM
// page visit). THE WRITE PATTERN, not the argmax, owns the residue.
//
// R12: block = (8 adjacent m's, 256 rows); 512 blocks x 512 threads;
// wave w <-> m = mg*8+w so k-loop LDS reads stay wave-uniform (R9
// invariant). 64KB C in LDS -> 2 blocks/CU, 16 waves/CU (= R11 occupancy).
//   - codes: per iteration the block writes 8KB CONTIGUOUS (8 m-segments
//     of one row), nontemporal stores (pure stream, like the fill).
//   - x: block reads 256B/row contiguous -> full-line use (134->33.5MB).
//   - xhat: 256B full-line writes, no cross-XCD partial-line RMW.
//   - blockIdx = rc*8+mg -> mg pinned to one XCD (C + x band L2-local).
// Bit-exact: same 4-chain shared-ca/cb k-loop as R11 (passed, absmax 0.0);
// P=xa*ca, Q=xb*cb, T=P+Q, dot=(T.x+T.y)+(T.z+T.w), contract off,
// strict > = first-max; one-hot same 4-compare form; xhat copies exact
// C words via LDS.

#define B_SZ   16384
#define FEAT   512
#define M_SZ   64
#define K_SZ   256
#define D_SZ   8

typedef float v4f __attribute__((ext_vector_type(4)));

// 512 blocks x 512 threads; block = (mg = blockIdx&7, rc = blockIdx>>3).
// wave w = m_local; lane l + chain c <-> local row l + 64c.
__global__ __launch_bounds__(512) void pq_fused(
    const float* __restrict__ x,
    const float* __restrict__ C,
    float* __restrict__ xhat,
    float* __restrict__ codes)
{
#pragma clang fp contract(off)   // np einsum: separate product roundings, no FMA

    const int t  = threadIdx.x;          // 0..511
    const int w  = t >> 6;               // wave 0..7 <-> m_local
    const int l  = t & 63;               // lane
    const int mg = blockIdx.x & 7;       // m-group (XCD-pinned)
    const int rc = blockIdx.x >> 3;      // row-chunk 0..63

    __shared__ v4f           Cs[8 * K_SZ * 2];   // 64KB: [m_local][k][half]
    __shared__ unsigned char lbk[256 * 8];       // [local_row][m_local]

    // ---- 1. stage C for the 8 m's: 64KB contiguous, coalesced ----
    {
        const v4f* src = (const v4f*)(C + (size_t)mg * (8 * K_SZ * D_SZ));
#pragma unroll
        for (int j = 0; j < 8; ++j)
            Cs[(j << 9) + t] = src[(j << 9) + t];
    }

    // ---- x loads: 4 rows/thread (local rows l, l+64, l+128, l+192) ----
    const int m = (mg << 3) | w;
    const float* xp0 = x + ((size_t)((rc << 8) | l)) * FEAT + m * D_SZ;
    const float* xp1 = xp0 + (size_t)64 * FEAT;
    const float* xp2 = xp1 + (size_t)64 * FEAT;
    const float* xp3 = xp2 + (size_t)64 * FEAT;
    const v4f xa0 = ((const v4f*)xp0)[0], xb0 = ((const v4f*)xp0)[1];
    const v4f xa1 = ((const v4f*)xp1)[0], xb1 = ((const v4f*)xp1)[1];
    const v4f xa2 = ((const v4f*)xp2)[0], xb2 = ((const v4f*)xp2)[1];
    const v4f xa3 = ((const v4f*)xp3)[0], xb3 = ((const v4f*)xp3)[1];

    __syncthreads();

    // ---- 2. argmax: wave w sweeps its own 8KB (uniform addr -> broadcast) ----
    const v4f* Cw = &Cs[w << 9];
    float best0 = -INFINITY, best1 = -INFINITY;
    float best2 = -INFINITY, best3 = -INFINITY;
    int   bk0 = 0, bk1 = 0, bk2 = 0, bk3 = 0;

#pragma unroll 2
    for (int k = 0; k < K_SZ; ++k) {
        const v4f ca = Cw[(k << 1) | 0];
        const v4f cb = Cw[(k << 1) | 1];

        v4f P0 = xa0 * ca, Q0 = xb0 * cb, T0 = P0 + Q0;
        float d0 = (T0.x + T0.y) + (T0.z + T0.w);
        v4f P1 = xa1 * ca, Q1 = xb1 * cb, T1 = P1 + Q1;
        float d1 = (T1.x + T1.y) + (T1.z + T1.w);
        v4f P2 = xa2 * ca, Q2 = xb2 * cb, T2 = P2 + Q2;
        float d2 = (T2.x + T2.y) + (T2.z + T2.w);
        v4f P3 = xa3 * ca, Q3 = xb3 * cb, T3 = P3 + Q3;
        float d3 = (T3.x + T3.y) + (T3.z + T3.w);

        if (d0 > best0) { best0 = d0; bk0 = k; }  // strict >: first max
        if (d1 > best1) { best1 = d1; bk1 = k; }
        if (d2 > best2) { best2 = d2; bk2 = k; }
        if (d3 > best3) { best3 = d3; bk3 = k; }
    }

    lbk[((l      ) << 3) | w] = (unsigned char)bk0;
    lbk[((l +  64) << 3) | w] = (unsigned char)bk1;
    lbk[((l + 128) << 3) | w] = (unsigned char)bk2;
    lbk[((l + 192) << 3) | w] = (unsigned char)bk3;
    __syncthreads();

    // ---- 3. codes: 256 iters; block writes 8KB CONTIGUOUS per iter ----
    const int lane4 = l << 2;
    v4f* const cbase = (v4f*)codes + ((size_t)rc << 20) + (size_t)((mg << 9) + t);

#pragma unroll 4
    for (int r = 0; r < 256; ++r) {
        const int kk = (int)lbk[(r << 3) | w];   // wave-uniform broadcast
        v4f v;
        v.x = (kk == lane4 + 0) ? 1.0f : 0.0f;
        v.y = (kk == lane4 + 1) ? 1.0f : 0.0f;
        v.z = (kk == lane4 + 2) ? 1.0f : 0.0f;
        v.w = (kk == lane4 + 3) ? 1.0f : 0.0f;
        __builtin_nontemporal_store(v, cbase + ((size_t)r << 12));
    }

    // ---- 4. xhat: 256B full-line rows, gathered from LDS ----
    {
        const int j    = t & 15;    // f4 within block's 64-float row slice
        const int m_l  = j >> 1;
        const int h    = j & 1;
        const int rb   = t >> 4;    // 0..31
        const v4f* Cm_ = &Cs[m_l << 9];
#pragma unroll
        for (int c = 0; c < 8; ++c) {
            const int r  = rb + (c << 5);
            const int kk = (int)lbk[(r << 3) | m_l];
            v4f* dst = (v4f*)(xhat + ((size_t)((rc << 8) | r)) * FEAT
                              + (mg << 6) + (j << 2));
            *dst = Cm_[(kk << 1) | h];
        }
    }
}

extern "C" void kernel_launch(void* const* d_in, const int* in_sizes, int n_in,
                              void* d_out, int out_size, void* d_ws, size_t ws_size,
                              hipStream_t stream)
{
    const float* x = (const float*)d_in[0];
    const float* C = (const float*)d_in[1];
    float* xhat  = (float*)d_out;                           // (B, 512)
    float* codes = (float*)d_out + (size_t)B_SZ * FEAT;     // (B, 64, 256)

    hipLaunchKernelGGL(pq_fused, dim3(512), dim3(512), 0, stream,
                       x, C, xhat, codes);
}

// Round 6
// 1153.605 us; speedup vs baseline: 1.0051x; 1.0051x over previous
//
#include <hip/hip_runtime.h>
#include <math.h>

// PQLayer forward, MI355X — R13: fused, 4-stage intra-block pipeline
//                               (stores of chain p-1 drain under argmax p).
//   x: (B,512) fp32   C: (64,256,8) fp32
//   out0 x_hat (B,512) = C[m,k*,:]   out1 codes (B,64,256) = one_hot(k*)
//
// Evidence R8-R12: every dataflow/locality change neutral; only structural
// phase deletion (R10 fusion, -44us) won. Model: F = fill 703 + ~120 tax
// (prior-session t1/t2 decomposition) -> fused kernel ~330us vs 181us HBM
// write floor. The unattacked slack: argmax (VALU/LDS) and codes stores
// (HBM) are serial phases in every block, phase-locked chip-wide -> HBM
// idles during argmax, VALU idles during stores.
//
// R13: 1024 blocks x 256 threads, 4 chains/thread, chains swept
// SEQUENTIALLY. Phase p: [issue 64 block-wide stores for chain p-1]
// -> [argmax chain p (256-iter k-loop) + xhat write] -> [lbk_p] -> barrier.
// Stores have no trailing vmcnt drain: they retire via L2->HBM in the
// background while the next argmax runs on VALU/LDS. lbk has a private
// region per chain (no WAR); x loaded upfront (no waitcnt entanglement
// with the store queue). Expected kernel ~A0 + 4 x drain ~ 200-240us.
// Bit-exact: per-row k-loop is the frozen R9/R10 single-row tree
// (P=xa*ca, Q=xb*cb, T=P+Q, dot=(T.x+T.y)+(T.z+T.w), contract off,
// strict > = first-max); store/xhat constructions are R10's, row-offset.

#define B_SZ   16384
#define FEAT   512
#define M_SZ   64
#define K_SZ   256
#define D_SZ   8

typedef float v4f __attribute__((ext_vector_type(4)));

// 1024 blocks x 256 threads; block = (m = blockIdx&63, chunk = blockIdx>>6).
// chain p of thread t <-> global row (chunk<<10)|(p<<8)|t.
__global__ __launch_bounds__(256) void pq_fused(
    const float* __restrict__ x,
    const float* __restrict__ C,
    float* __restrict__ xhat,
    float* __restrict__ codes)
{
#pragma clang fp contract(off)   // np einsum: separate product roundings, no FMA

    const int t     = threadIdx.x;
    const int m     = blockIdx.x & (M_SZ - 1);   // block-uniform m
    const int chunk = blockIdx.x >> 6;           // 0..15
    const int w     = t >> 6;                    // wave 0..3
    const int lane  = t & 63;
    const int lane4 = lane << 2;

    __shared__ v4f           Cs[K_SZ * 2];   // 8KB; row k: (d0..3),(d4..7)
    __shared__ unsigned char lbk[4 * 256];   // [chain][local row]

    // ---- stage C[m]: thread t copies row t (32B), coalesced 8KB ----
    {
        const v4f* src = (const v4f*)(C + (size_t)m * (K_SZ * D_SZ)) + (t << 1);
        Cs[(t << 1) | 0] = src[0];
        Cs[(t << 1) | 1] = src[1];
    }

    // ---- x for all 4 chains upfront (keeps store queue free of read waits) ----
#define XLOAD(p, XA, XB)                                                        \
    const float* xp##p = x + ((size_t)((chunk << 10) | (p << 8) | t)) * FEAT    \
                           + m * D_SZ;                                          \
    const v4f XA = ((const v4f*)xp##p)[0];                                      \
    const v4f XB = ((const v4f*)xp##p)[1];
    XLOAD(0, xa0, xb0)
    XLOAD(1, xa1, xb1)
    XLOAD(2, xa2, xb2)
    XLOAD(3, xa3, xb3)
#undef XLOAD

    __syncthreads();

    // ---- frozen single-row argmax sweep (bit-exact R9/R10 loop) ----
#define ARGMAX(XA, XB, BK)                                                      \
    int BK;                                                                     \
    {                                                                           \
        float best = -INFINITY; int bk_ = 0;                                    \
        _Pragma("unroll 4")                                                     \
        for (int k = 0; k < K_SZ; ++k) {                                        \
            const v4f ca = Cs[(k << 1) | 0];   /* uniform -> broadcast */       \
            const v4f cb = Cs[(k << 1) | 1];                                    \
            v4f P = (XA) * ca;                 /* v_pk_mul_f32 x2 */            \
            v4f Q = (XB) * cb;                                                  \
            v4f T = P + Q;                     /* v_pk_add_f32 x2 */            \
            float dot = (T.x + T.y) + (T.z + T.w);   /* np tree */              \
            if (dot > best) { best = dot; bk_ = k; }  /* strict >: first max */ \
        }                                                                       \
        BK = bk_;                                                               \
    }

    // ---- xhat for chain p's row, gathered from LDS (same bits as C) ----
#define XHAT(p, BK)                                                             \
    {                                                                           \
        float* xh = xhat + ((size_t)((chunk << 10) | (p << 8) | t)) * FEAT      \
                         + m * D_SZ;                                            \
        ((v4f*)xh)[0] = Cs[(BK << 1) | 0];                                      \
        ((v4f*)xh)[1] = Cs[(BK << 1) | 1];                                      \
    }

    // ---- codes stores for chain p: 64 block-wide 1KB-contiguous iters ----
    // Issued with NO trailing vmcnt drain; retires under the next argmax.
#define STORES(p)                                                               \
    {                                                                           \
        const size_t rowbase = (size_t)((chunk << 10) | (p << 8));              \
        _Pragma("unroll 4")                                                     \
        for (int j = 0; j < 64; ++j) {                                          \
            const int i  = (j << 2) | w;                                        \
            const int kk = (int)lbk[(p << 8) | i];   /* LDS broadcast */        \
            float4 v;                                                           \
            v.x = (kk == lane4 + 0) ? 1.0f : 0.0f;                              \
            v.y = (kk == lane4 + 1) ? 1.0f : 0.0f;                              \
            v.z = (kk == lane4 + 2) ? 1.0f : 0.0f;                              \
            v.w = (kk == lane4 + 3) ? 1.0f : 0.0f;                              \
            ((float4*)codes)[((rowbase + i) << 12) + (m << 6) + lane] = v;      \
        }                                                                       \
    }

    // ---- 4-stage pipeline ----
    ARGMAX(xa0, xb0, bk0)
    XHAT(0, bk0)
    lbk[(0 << 8) | t] = (unsigned char)bk0;
    __syncthreads();

    STORES(0)                  // drains under chain-1 argmax
    ARGMAX(xa1, xb1, bk1)
    XHAT(1, bk1)
    lbk[(1 << 8) | t] = (unsigned char)bk1;
    __syncthreads();

    STORES(1)                  // drains under chain-2 argmax
    ARGMAX(xa2, xb2, bk2)
    XHAT(2, bk2)
    lbk[(2 << 8) | t] = (unsigned char)bk2;
    __syncthreads();

    STORES(2)                  // drains under chain-3 argmax
    ARGMAX(xa3, xb3, bk3)
    XHAT(3, bk3)
    lbk[(3 << 8) | t] = (unsigned char)bk3;
    __syncthreads();

    STORES(3)                  // final drain (exposed tail)

#undef ARGMAX
#undef XHAT
#undef STORES
}

extern "C" void kernel_launch(void* const* d_in, const int* in_sizes, int n_in,
                              void* d_out, int out_size, void* d_ws, size_t ws_size,
                              hipStream_t stream)
{
    const float* x = (const float*)d_in[0];
    const float* C = (const float*)d_in[1];
    float* xhat  = (float*)d_out;                           // (B, 512)
    float* codes = (float*)d_out + (size_t)B_SZ * FEAT;     // (B, 64, 256)

    hipLaunchKernelGGL(pq_fused, dim3(1024), dim3(256), 0, stream,
                       x, C, xhat, codes);
}